// Round 9
// baseline (127.282 us; speedup 1.0000x reference)
//
#include <hip/hip_runtime.h>
#include <math.h>

#define N_V 100000
#define N_J 24
#define N_BETAS 300
#define N_POSE 207
#define NBLKV (N_V / 16)       // 6250 vertex blocks

typedef float f4 __attribute__((ext_vector_type(4)));

__constant__ int c_parents[N_J] = {0,0,0,0,1,2,3,4,5,6,7,8,9,9,9,12,13,14,16,17,18,19,20,21};

__device__ inline void rodrigues9(const float* __restrict__ pose, int j, float R[9]) {
    float x = pose[j*3+0], y = pose[j*3+1], z = pose[j*3+2];
    float th = sqrtf(x*x + y*y + z*z + 1e-16f);
    float inv = 1.0f / th;
    float rx = x*inv, ry = y*inv, rz = z*inv;
    float c = cosf(th), s = sinf(th), o = 1.0f - c;
    R[0] = c + o*rx*rx;      R[1] = o*rx*ry - s*rz;  R[2] = o*rx*rz + s*ry;
    R[3] = o*ry*rx + s*rz;   R[4] = c + o*ry*ry;     R[5] = o*ry*rz - s*rx;
    R[6] = o*rz*rx - s*ry;   R[7] = o*rz*ry + s*rx;  R[8] = c + o*rz*rz;
}

// ---------------- K1: vertex (v_shaped+v_posed) + coalesced J partials -----
// block = 16 contiguous vertices, wave = 4 verts. vp is SoA [3][N_V].
// jpart layout: [72][NBLKV]
__global__ __launch_bounds__(256) void k_vertex(
        const float* __restrict__ shapedirs, const float* __restrict__ posedirs,
        const float* __restrict__ v_template, const float* __restrict__ beta,
        const float* __restrict__ pose, const float* __restrict__ Jr,
        float* __restrict__ vp, float* __restrict__ jpart) {
    __shared__ float lrot_s[N_POSE];
    __shared__ float vsh[16][3];
    int t = threadIdx.x;
    int lane = t & 63, wave = t >> 6;

    // ---- block-local lrotmin (joints 1..23)
    if (t >= 1 && t < N_J) {
        float R[9]; rodrigues9(pose, t, R);
        #pragma unroll
        for (int e = 0; e < 9; ++e)
            lrot_s[(t-1)*9 + e] = R[e] - ((e==0 || e==4 || e==8) ? 1.f : 0.f);
    }
    __syncthreads();

    // ---- per-wave operand registers (amortized over 4 verts)
    f4 bv[4];
    #pragma unroll
    for (int it = 0; it < 4; ++it) {
        int i = lane + it * 64;
        int d = (i >= 150) ? 2 : ((i >= 75) ? 1 : 0);
        int k4 = i - d * 75;
        if (it < 3 || i < 225) bv[it] = ((const f4*)beta)[k4];
        else                   bv[it] = (f4){0.f, 0.f, 0.f, 0.f};
    }
    int f0 = 4 * lane;
    f4 lrc0 = { lrot_s[(f0+0)%207], lrot_s[(f0+1)%207], lrot_s[(f0+2)%207], lrot_s[(f0+3)%207] };
    f4 lrc1 = { lrot_s[(f0+256)%207], lrot_s[(f0+257)%207], lrot_s[(f0+258)%207], lrot_s[(f0+259)%207] };
    f4 lrc2 = { lrot_s[(f0+512)%207], lrot_s[(f0+513)%207], lrot_s[(f0+514)%207], lrot_s[(f0+515)%207] };
    float tc = lrot_s[206];

    int vb = blockIdx.x * 16 + wave * 4;

    #pragma unroll 2
    for (int u = 0; u < 4; ++u) {
        int v = vb + u;
        const f4*    sb = (const f4*)(shapedirs + (size_t)v * 900);
        const float* pb = posedirs + (size_t)v * 621;

        f4 s0 = __builtin_nontemporal_load(sb + lane);
        f4 s1 = __builtin_nontemporal_load(sb + lane + 64);
        f4 s2 = __builtin_nontemporal_load(sb + lane + 128);
        f4 s3 = (lane < 33) ? __builtin_nontemporal_load(sb + lane + 192)
                            : (f4){0.f, 0.f, 0.f, 0.f};
        f4 x0, x1, x2 = (f4){0.f, 0.f, 0.f, 0.f};
        __builtin_memcpy(&x0, pb + f0, 16);
        __builtin_memcpy(&x1, pb + f0 + 256, 16);
        if (lane < 27) __builtin_memcpy(&x2, pb + f0 + 512, 16);
        float tail = (lane == 27) ? pb[620] : 0.f;

        float a0 = 0.f, a1 = 0.f, a2 = 0.f;
        float p0 = 0.f, p1 = 0.f, p2 = 0.f;

        float c0 = s0.x*bv[0].x + s0.y*bv[0].y + s0.z*bv[0].z + s0.w*bv[0].w;
        float c1 = s1.x*bv[1].x + s1.y*bv[1].y + s1.z*bv[1].z + s1.w*bv[1].w;
        float c2 = s2.x*bv[2].x + s2.y*bv[2].y + s2.z*bv[2].z + s2.w*bv[2].w;
        float c3 = s3.x*bv[3].x + s3.y*bv[3].y + s3.z*bv[3].z + s3.w*bv[3].w;
        a0 += c0;
        if (lane < 11) a0 += c1; else a1 += c1;     // straddles f4 75
        if (lane < 22) a1 += c2; else a2 += c2;     // straddles f4 150
        a2 += c3;

        float d0 = x0.x*lrc0.x + x0.y*lrc0.y + x0.z*lrc0.z + x0.w*lrc0.w;
        float d1 = x1.x*lrc1.x + x1.y*lrc1.y + x1.z*lrc1.z + x1.w*lrc1.w;
        float d2 = x2.x*lrc2.x + x2.y*lrc2.y + x2.z*lrc2.z + x2.w*lrc2.w;
        if (lane < 51)       p0 += d0;
        else if (lane == 51) { float hi = x0.w * lrc0.w; p0 += d0 - hi; p1 += hi; }
        else                 p1 += d0;
        if (lane < 39)       p1 += d1;
        else if (lane == 39) { float hi = x1.z*lrc1.z + x1.w*lrc1.w; p1 += d1 - hi; p2 += hi; }
        else                 p2 += d1;
        p2 += d2 + tail * tc;

        #pragma unroll
        for (int off = 1; off <= 4; off <<= 1) {
            a0 += __shfl_xor(a0, off); a1 += __shfl_xor(a1, off); a2 += __shfl_xor(a2, off);
            p0 += __shfl_xor(p0, off); p1 += __shfl_xor(p1, off); p2 += __shfl_xor(p2, off);
        }
        int j = lane & 7;
        float val = a0;
        val = (j == 1) ? a1 : val;
        val = (j == 2) ? a2 : val;
        val = (j == 3) ? p0 : val;
        val = (j == 4) ? p1 : val;
        val = (j == 5) ? p2 : val;
        val += __shfl_xor(val, 8);
        val += __shfl_xor(val, 16);
        val += __shfl_xor(val, 32);
        float pj = __shfl(val, lane + 3);

        if (lane < 3) {
            float vsd = val + v_template[(size_t)v*3 + lane];
            vsh[wave*4 + u][lane] = vsd;
            vp[lane * N_V + v] = vsd + pj;
        }
    }
    __syncthreads();

    // ---- J partials: 24 joints x 16 verts, fully coalesced (24 lines/block)
    for (int idx = t; idx < N_J * 16; idx += 256) {
        int j = idx >> 4, vi = idx & 15;
        float w = __builtin_nontemporal_load(Jr + (size_t)j * N_V + blockIdx.x * 16 + vi);
        float s0 = w * vsh[vi][0];
        float s1 = w * vsh[vi][1];
        float s2 = w * vsh[vi][2];
        #pragma unroll
        for (int off = 1; off <= 8; off <<= 1) {
            s0 += __shfl_xor(s0, off); s1 += __shfl_xor(s1, off); s2 += __shfl_xor(s2, off);
        }
        if ((lane & 15) == 0) {
            jpart[(size_t)(j*3+0) * NBLKV + blockIdx.x] = s0;
            jpart[(size_t)(j*3+1) * NBLKV + blockIdx.x] = s1;
            jpart[(size_t)(j*3+2) * NBLKV + blockIdx.x] = s2;
        }
    }
}

// ---------------- K2: reduce jpart columns -> Jg[72] -----------------------
__global__ __launch_bounds__(256) void k_jreduce(const float* __restrict__ jpart,
                                                 float* __restrict__ Jg) {
    int c = blockIdx.x;           // 0..71
    const float* col = jpart + (size_t)c * NBLKV;
    int t = threadIdx.x;
    float s = 0.f;
    for (int i = t; i < NBLKV; i += 256) s += col[i];
    #pragma unroll
    for (int off = 32; off; off >>= 1) s += __shfl_xor(s, off);
    __shared__ float red[4];
    int wave = t >> 6, lane = t & 63;
    if (lane == 0) red[wave] = s;
    __syncthreads();
    if (t == 0) Jg[c] = red[0] + red[1] + red[2] + red[3];
}

// ---------------- K3: rodrigues + chain (per block) + skinning -------------
__global__ __launch_bounds__(256) void k_skin(const float* __restrict__ w,
                                              const float* __restrict__ Jg,
                                              const float* __restrict__ pose,
                                              const float* __restrict__ vp,
                                              float* __restrict__ out) {
    __shared__ float Rsh[N_J][9];
    __shared__ float J[N_J][3];
    __shared__ float G[N_J][16];
    __shared__ float Gp[N_J * 12];
    int t = threadIdx.x;
    if (t < N_J) {
        float R[9]; rodrigues9(pose, t, R);
        #pragma unroll
        for (int e = 0; e < 9; ++e) Rsh[t][e] = R[e];
    }
    if (t < N_J * 3) J[t/3][t%3] = Jg[t];
    __syncthreads();
    if (t < 16) {
        int a = t / 4, b = t % 4;
        float g;
        if (a < 3) g = (b < 3) ? Rsh[0][a*3 + b] : J[0][a];
        else       g = (b == 3) ? 1.f : 0.f;
        G[0][t] = g;
    }
    __syncthreads();
    for (int i = 1; i < N_J; ++i) {
        int p = c_parents[i];
        if (t < 16) {
            int a = t / 4, b = t % 4;
            float acc = 0.f;
            #pragma unroll
            for (int k = 0; k < 4; ++k) {
                float Ak;
                if (k < 3) Ak = (b < 3) ? Rsh[i][k*3 + b] : (J[i][k] - J[p][k]);
                else       Ak = (b == 3) ? 1.f : 0.f;
                acc += G[p][a*4 + k] * Ak;
            }
            G[i][t] = acc;
        }
        __syncthreads();
    }
    for (int i = t; i < N_J * 12; i += 256) {    // 288 > 256: strided loop
        int j = i / 12, r = i % 12, a = r / 4, b = r % 4;
        float g = G[j][a*4 + b];
        if (b == 3)
            g -= G[j][a*4+0]*J[j][0] + G[j][a*4+1]*J[j][1] + G[j][a*4+2]*J[j][2];
        Gp[i] = g;
    }
    __syncthreads();

    int v = blockIdx.x * 256 + t;
    if (v >= N_V) return;
    float T[12];
    #pragma unroll
    for (int r = 0; r < 12; ++r) T[r] = 0.f;
    const f4* wv = (const f4*)(w + (size_t)v * 24);
    #pragma unroll
    for (int q = 0; q < 6; ++q) {
        f4 ww = __builtin_nontemporal_load(wv + q);
        float wj[4] = {ww.x, ww.y, ww.z, ww.w};
        #pragma unroll
        for (int jj = 0; jj < 4; ++jj) {
            const float* g = &Gp[(q*4 + jj) * 12];
            #pragma unroll
            for (int r = 0; r < 12; ++r) T[r] += wj[jj] * g[r];
        }
    }
    float px = vp[v], py = vp[N_V + v], pz = vp[2*N_V + v];
    out[v*3+0] = T[0]*px + T[1]*py + T[2]*pz  + T[3];
    out[v*3+1] = T[4]*px + T[5]*py + T[6]*pz  + T[7];
    out[v*3+2] = T[8]*px + T[9]*py + T[10]*pz + T[11];
}

// ---------------- launcher --------------------------------------------------
extern "C" void kernel_launch(void* const* d_in, const int* in_sizes, int n_in,
                              void* d_out, int out_size, void* d_ws, size_t ws_size,
                              hipStream_t stream) {
    const float* beta       = (const float*)d_in[0];
    const float* pose       = (const float*)d_in[1];
    const float* v_template = (const float*)d_in[2];
    const float* Jr         = (const float*)d_in[3];
    const float* skin_w     = (const float*)d_in[4];
    const float* shapedirs  = (const float*)d_in[5];
    const float* posedirs   = (const float*)d_in[6];
    float* out = (float*)d_out;

    float* ws    = (float*)d_ws;
    float* ws_vp = ws;                    // 3*N_V (SoA)
    float* ws_jp = ws + 3*N_V;            // 72*NBLKV = 450000
    float* ws_J  = ws + 3*N_V + 72*NBLKV; // 72

    k_vertex<<<NBLKV, 256, 0, stream>>>(shapedirs, posedirs, v_template,
                                        beta, pose, Jr, ws_vp, ws_jp);
    k_jreduce<<<N_J * 3, 256, 0, stream>>>(ws_jp, ws_J);
    k_skin<<<(N_V + 255) / 256, 256, 0, stream>>>(skin_w, ws_J, pose, ws_vp, out);
}

// Round 10
// 114.714 us; speedup vs baseline: 1.1096x; 1.1096x over previous
//
#include <hip/hip_runtime.h>
#include <math.h>

#define N_V 100000
#define N_J 24
#define N_BETAS 300
#define N_POSE 207
#define JSPLIT 25

typedef float f4 __attribute__((ext_vector_type(4)));

__constant__ int c_parents[N_J] = {0,0,0,0,1,2,3,4,5,6,7,8,9,9,9,12,13,14,16,17,18,19,20,21};

__device__ inline void rodrigues9(const float* __restrict__ pose, int j, float R[9]) {
    float x = pose[j*3+0], y = pose[j*3+1], z = pose[j*3+2];
    float th = sqrtf(x*x + y*y + z*z + 1e-16f);
    float inv = 1.0f / th;
    float rx = x*inv, ry = y*inv, rz = z*inv;
    float c = cosf(th), s = sinf(th), o = 1.0f - c;
    R[0] = c + o*rx*rx;      R[1] = o*rx*ry - s*rz;  R[2] = o*rx*rz + s*ry;
    R[3] = o*ry*rx + s*rz;   R[4] = c + o*ry*ry;     R[5] = o*ry*rz - s*rx;
    R[6] = o*rz*rx - s*ry;   R[7] = o*rz*ry + s*rx;  R[8] = c + o*rz*rz;
}

// ---------------- K1: block = 16 contiguous vertices, wave = 4 -------------
// vs / vp are SoA: [3][N_V]. lrotmin computed per block (no separate kernel).
__global__ __launch_bounds__(256) void k_vertex(
        const float* __restrict__ shapedirs, const float* __restrict__ posedirs,
        const float* __restrict__ v_template, const float* __restrict__ beta,
        const float* __restrict__ pose,
        float* __restrict__ vs, float* __restrict__ vp) {
    __shared__ float lrot_s[N_POSE];
    int t = threadIdx.x;
    int lane = t & 63, wave = t >> 6;

    // ---- block-local lrotmin (joints 1..23)
    if (t >= 1 && t < N_J) {
        float R[9]; rodrigues9(pose, t, R);
        #pragma unroll
        for (int e = 0; e < 9; ++e)
            lrot_s[(t-1)*9 + e] = R[e] - ((e==0 || e==4 || e==8) ? 1.f : 0.f);
    }
    __syncthreads();

    // ---- per-wave operand registers (amortized over 4 verts)
    f4 bv[4];
    #pragma unroll
    for (int it = 0; it < 4; ++it) {
        int i = lane + it * 64;
        int d = (i >= 150) ? 2 : ((i >= 75) ? 1 : 0);
        int k4 = i - d * 75;
        if (it < 3 || i < 225) bv[it] = ((const f4*)beta)[k4];
        else                   bv[it] = (f4){0.f, 0.f, 0.f, 0.f};
    }
    int f0 = 4 * lane;
    f4 lrc0 = { lrot_s[(f0+0)%207], lrot_s[(f0+1)%207], lrot_s[(f0+2)%207], lrot_s[(f0+3)%207] };
    f4 lrc1 = { lrot_s[(f0+256)%207], lrot_s[(f0+257)%207], lrot_s[(f0+258)%207], lrot_s[(f0+259)%207] };
    f4 lrc2 = { lrot_s[(f0+512)%207], lrot_s[(f0+513)%207], lrot_s[(f0+514)%207], lrot_s[(f0+515)%207] };
    float tc = lrot_s[206];

    int vb = blockIdx.x * 16 + wave * 4;

    #pragma unroll 2
    for (int u = 0; u < 4; ++u) {
        int v = vb + u;
        const f4*    sb = (const f4*)(shapedirs + (size_t)v * 900);
        const float* pb = posedirs + (size_t)v * 621;

        f4 s0 = __builtin_nontemporal_load(sb + lane);
        f4 s1 = __builtin_nontemporal_load(sb + lane + 64);
        f4 s2 = __builtin_nontemporal_load(sb + lane + 128);
        f4 s3 = (lane < 33) ? __builtin_nontemporal_load(sb + lane + 192)
                            : (f4){0.f, 0.f, 0.f, 0.f};
        f4 x0, x1, x2 = (f4){0.f, 0.f, 0.f, 0.f};
        __builtin_memcpy(&x0, pb + f0, 16);
        __builtin_memcpy(&x1, pb + f0 + 256, 16);
        if (lane < 27) __builtin_memcpy(&x2, pb + f0 + 512, 16);
        float tail = (lane == 27) ? pb[620] : 0.f;

        float a0 = 0.f, a1 = 0.f, a2 = 0.f;
        float p0 = 0.f, p1 = 0.f, p2 = 0.f;

        float c0 = s0.x*bv[0].x + s0.y*bv[0].y + s0.z*bv[0].z + s0.w*bv[0].w;
        float c1 = s1.x*bv[1].x + s1.y*bv[1].y + s1.z*bv[1].z + s1.w*bv[1].w;
        float c2 = s2.x*bv[2].x + s2.y*bv[2].y + s2.z*bv[2].z + s2.w*bv[2].w;
        float c3 = s3.x*bv[3].x + s3.y*bv[3].y + s3.z*bv[3].z + s3.w*bv[3].w;
        a0 += c0;
        if (lane < 11) a0 += c1; else a1 += c1;     // straddles f4 75
        if (lane < 22) a1 += c2; else a2 += c2;     // straddles f4 150
        a2 += c3;

        float d0 = x0.x*lrc0.x + x0.y*lrc0.y + x0.z*lrc0.z + x0.w*lrc0.w;
        float d1 = x1.x*lrc1.x + x1.y*lrc1.y + x1.z*lrc1.z + x1.w*lrc1.w;
        float d2 = x2.x*lrc2.x + x2.y*lrc2.y + x2.z*lrc2.z + x2.w*lrc2.w;
        if (lane < 51)       p0 += d0;
        else if (lane == 51) { float hi = x0.w * lrc0.w; p0 += d0 - hi; p1 += hi; }
        else                 p1 += d0;
        if (lane < 39)       p1 += d1;
        else if (lane == 39) { float hi = x1.z*lrc1.z + x1.w*lrc1.w; p1 += d1 - hi; p2 += hi; }
        else                 p2 += d1;
        p2 += d2 + tail * tc;

        #pragma unroll
        for (int off = 1; off <= 4; off <<= 1) {
            a0 += __shfl_xor(a0, off); a1 += __shfl_xor(a1, off); a2 += __shfl_xor(a2, off);
            p0 += __shfl_xor(p0, off); p1 += __shfl_xor(p1, off); p2 += __shfl_xor(p2, off);
        }
        int j = lane & 7;
        float val = a0;
        val = (j == 1) ? a1 : val;
        val = (j == 2) ? a2 : val;
        val = (j == 3) ? p0 : val;
        val = (j == 4) ? p1 : val;
        val = (j == 5) ? p2 : val;
        val += __shfl_xor(val, 8);
        val += __shfl_xor(val, 16);
        val += __shfl_xor(val, 32);
        float pj = __shfl(val, lane + 3);

        if (lane < 3) {
            float vsd = val + v_template[(size_t)v*3 + lane];
            vs[lane * N_V + v] = vsd;
            vp[lane * N_V + v] = vsd + pj;
        }
    }
}

// ---------------- K2: J partials (float4 over SoA v_shaped) ----------------
__global__ __launch_bounds__(256) void k_jreg(const float* __restrict__ Jr,
                                              const float* __restrict__ vs,
                                              float* __restrict__ jpart) {
    int j = blockIdx.x / JSPLIT;
    int s = blockIdx.x % JSPLIT;
    const int chunk4 = (N_V / JSPLIT) / 4;   // 1000 float4
    int b4 = s * chunk4;
    int t = threadIdx.x;
    const f4* row = (const f4*)(Jr + (size_t)j * N_V);
    const f4* X = (const f4*)(vs);
    const f4* Y = (const f4*)(vs + N_V);
    const f4* Z = (const f4*)(vs + 2 * N_V);
    float a0 = 0.f, a1 = 0.f, a2 = 0.f;
    for (int i = b4 + t; i < b4 + chunk4; i += 256) {
        f4 w = row[i];
        f4 x = X[i], y = Y[i], z = Z[i];
        a0 += w.x*x.x + w.y*x.y + w.z*x.z + w.w*x.w;
        a1 += w.x*y.x + w.y*y.y + w.z*y.z + w.w*y.w;
        a2 += w.x*z.x + w.y*z.y + w.z*z.z + w.w*z.w;
    }
    #pragma unroll
    for (int off = 32; off; off >>= 1) {
        a0 += __shfl_xor(a0, off); a1 += __shfl_xor(a1, off); a2 += __shfl_xor(a2, off);
    }
    __shared__ float red[4][3];
    int wave = t >> 6, lane = t & 63;
    if (lane == 0) { red[wave][0] = a0; red[wave][1] = a1; red[wave][2] = a2; }
    __syncthreads();
    if (t == 0) {
        jpart[(j*JSPLIT+s)*3+0] = red[0][0]+red[1][0]+red[2][0]+red[3][0];
        jpart[(j*JSPLIT+s)*3+1] = red[0][1]+red[1][1]+red[2][1]+red[3][1];
        jpart[(j*JSPLIT+s)*3+2] = red[0][2]+red[1][2]+red[2][2]+red[3][2];
    }
}

// ---------------- K3: rodrigues + J-reduce + chain (per block) + skinning --
__global__ __launch_bounds__(256) void k_skin(const float* __restrict__ w,
                                              const float* __restrict__ jpart,
                                              const float* __restrict__ pose,
                                              const float* __restrict__ vp,
                                              float* __restrict__ out) {
    __shared__ float Rsh[N_J][9];
    __shared__ float J[N_J][3];
    __shared__ float G[N_J][16];
    __shared__ float Gp[N_J * 12];
    int t = threadIdx.x;
    if (t < N_J) {
        float R[9]; rodrigues9(pose, t, R);
        #pragma unroll
        for (int e = 0; e < 9; ++e) Rsh[t][e] = R[e];
    }
    if (t >= 64 && t < 64 + N_J * 3) {
        int i = t - 64;
        int j = i / 3, d = i % 3;
        float s = 0.f;
        #pragma unroll
        for (int k = 0; k < JSPLIT; ++k) s += jpart[(j*JSPLIT+k)*3 + d];
        J[j][d] = s;
    }
    __syncthreads();
    if (t < 16) {
        int a = t / 4, b = t % 4;
        float g;
        if (a < 3) g = (b < 3) ? Rsh[0][a*3 + b] : J[0][a];
        else       g = (b == 3) ? 1.f : 0.f;
        G[0][t] = g;
    }
    __syncthreads();
    for (int i = 1; i < N_J; ++i) {
        int p = c_parents[i];
        if (t < 16) {
            int a = t / 4, b = t % 4;
            float acc = 0.f;
            #pragma unroll
            for (int k = 0; k < 4; ++k) {
                float Ak;
                if (k < 3) Ak = (b < 3) ? Rsh[i][k*3 + b] : (J[i][k] - J[p][k]);
                else       Ak = (b == 3) ? 1.f : 0.f;
                acc += G[p][a*4 + k] * Ak;
            }
            G[i][t] = acc;
        }
        __syncthreads();
    }
    for (int i = t; i < N_J * 12; i += 256) {    // 288 > 256: strided loop
        int j = i / 12, r = i % 12, a = r / 4, b = r % 4;
        float g = G[j][a*4 + b];
        if (b == 3)
            g -= G[j][a*4+0]*J[j][0] + G[j][a*4+1]*J[j][1] + G[j][a*4+2]*J[j][2];
        Gp[i] = g;
    }
    __syncthreads();

    int v = blockIdx.x * 256 + t;
    if (v >= N_V) return;
    float T[12];
    #pragma unroll
    for (int r = 0; r < 12; ++r) T[r] = 0.f;
    const f4* wv = (const f4*)(w + (size_t)v * 24);
    #pragma unroll
    for (int q = 0; q < 6; ++q) {
        f4 ww = __builtin_nontemporal_load(wv + q);
        float wj[4] = {ww.x, ww.y, ww.z, ww.w};
        #pragma unroll
        for (int jj = 0; jj < 4; ++jj) {
            const float* g = &Gp[(q*4 + jj) * 12];
            #pragma unroll
            for (int r = 0; r < 12; ++r) T[r] += wj[jj] * g[r];
        }
    }
    float px = vp[v], py = vp[N_V + v], pz = vp[2*N_V + v];
    out[v*3+0] = T[0]*px + T[1]*py + T[2]*pz  + T[3];
    out[v*3+1] = T[4]*px + T[5]*py + T[6]*pz  + T[7];
    out[v*3+2] = T[8]*px + T[9]*py + T[10]*pz + T[11];
}

// ---------------- launcher --------------------------------------------------
extern "C" void kernel_launch(void* const* d_in, const int* in_sizes, int n_in,
                              void* d_out, int out_size, void* d_ws, size_t ws_size,
                              hipStream_t stream) {
    const float* beta       = (const float*)d_in[0];
    const float* pose       = (const float*)d_in[1];
    const float* v_template = (const float*)d_in[2];
    const float* Jr         = (const float*)d_in[3];
    const float* skin_w     = (const float*)d_in[4];
    const float* shapedirs  = (const float*)d_in[5];
    const float* posedirs   = (const float*)d_in[6];
    float* out = (float*)d_out;

    float* ws    = (float*)d_ws;
    float* ws_vs = ws;              // 3*N_V (SoA)
    float* ws_vp = ws + 3*N_V;      // 3*N_V (SoA)
    float* ws_jp = ws + 6*N_V;      // 24*25*3 = 1800

    k_vertex<<<N_V / 16, 256, 0, stream>>>(shapedirs, posedirs, v_template,
                                           beta, pose, ws_vs, ws_vp);
    k_jreg<<<N_J * JSPLIT, 256, 0, stream>>>(Jr, ws_vs, ws_jp);
    k_skin<<<(N_V + 255) / 256, 256, 0, stream>>>(skin_w, ws_jp, pose, ws_vp, out);
}